// Round 13
// baseline (592.920 us; speedup 1.0000x reference)
//
#include <hip/hip_runtime.h>

#define TOBS  50
#define SDEC  100
#define HID   128
#define EMB   64
#define MD    256
#define M2N   112
#define NZ    16
#define ROWS  32
#define KPAD  140           // shorts; 70-dw row stride (proven low-conflict across R2-R12)
#define H1PAD 264
#define CHUNK 40
#define L2E   1.4426950408889634f
#define TL2E  2.8853900817779268f

using bf16x8 = __attribute__((ext_vector_type(8))) short;
using f32x4  = __attribute__((ext_vector_type(4))) float;
#define MFMA __builtin_amdgcn_mfma_f32_16x16x32_bf16

// LDS: 131072 + 17920 + 10240 + 4096 = 163328 B  (<= 160 KiB)
struct alignas(16) SMem {
  uint4 wfr[8][4][4][64];            // B-frags [j][g][kt][lane]; also MLP-h1 scratch
  unsigned short h[2][ROWS * KPAD];  // h double buffer (bf16)
  unsigned char ub[10240];           // prep{offsb,cl0,cl1,offlast,delta} / decoder outst chunk
  uint4 b5f[4][64];                  // readout Wr frags [kt][lane]
};

__device__ __forceinline__ unsigned int rnd16(float x){
  return __builtin_bit_cast(unsigned int, x) + 0x8000u;
}
__device__ __forceinline__ unsigned int pkbf(float a, float b){
  return __builtin_amdgcn_perm(rnd16(b), rnd16(a), 0x07060302u);  // lo=bf16(a), hi=bf16(b)
}
__device__ __forceinline__ unsigned short bfs(float x){ return (unsigned short)(rnd16(x) >> 16); }
__device__ __forceinline__ float lo2f(unsigned int u){ return __builtin_bit_cast(float, u << 16); }
__device__ __forceinline__ float hi2f(unsigned int u){ return __builtin_bit_cast(float, u & 0xFFFF0000u); }
__device__ __forceinline__ float rcpf(float x){ return __builtin_amdgcn_rcpf(x); }
__device__ __forceinline__ float ex2(float x){ return __builtin_amdgcn_exp2f(x); }
__device__ __forceinline__ bf16x8 pack8s(const float* p, float s){
  float4 a = *(const float4*)(p);
  float4 b = *(const float4*)(p + 4);
  uint4 u;
  u.x = pkbf(s*a.x, s*a.y); u.y = pkbf(s*a.z, s*a.w);
  u.z = pkbf(s*b.x, s*b.y); u.w = pkbf(s*b.z, s*b.w);
  return __builtin_bit_cast(bf16x8, u);
}
__device__ __forceinline__ bf16x8 pack8(const float* p){ return pack8s(p, 1.0f); }

// one LSTM output row: consumes acc[0..3][R], updates cst[R], writes hn
#define ELEM_R(R) do { \
  float ei_ = ex2(acc[0][R]), ef_ = ex2(acc[1][R]); \
  float eg_ = ex2(acc[2][R]), eo_ = ex2(acc[3][R]); \
  float a1_ = 1.0f + ef_, a2_ = 1.0f + ei_, a3_ = 1.0f + eg_; \
  float P_  = a2_ * a3_; \
  float rD_ = rcpf(a1_ * P_); \
  float N_  = __builtin_fmaf(cst[R], P_, (1.0f - eg_) * a1_); \
  float cn_ = N_ * rD_; \
  cst[R] = cn_; \
  float em_ = ex2(cn_ * (-TL2E)); \
  float rQ_ = rcpf((1.0f + eo_) * (1.0f + em_)); \
  float hh_ = (1.0f - em_) * rQ_; \
  hn[(hrow0 + (R))*KPAD + colj] = bfs(hh_); \
} while(0)

extern "C" __global__ void __launch_bounds__(1024, 4)
seqgen(const float* __restrict__ obs,
       const float* __restrict__ We,    const float* __restrict__ be,
       const float* __restrict__ Wih_e, const float* __restrict__ Whh_e, const float* __restrict__ b_e,
       const float* __restrict__ Wm1,   const float* __restrict__ bm1,
       const float* __restrict__ Wm2,   const float* __restrict__ bm2,
       const float* __restrict__ Wd,    const float* __restrict__ bd,
       const float* __restrict__ Wih_d, const float* __restrict__ Whh_d, const float* __restrict__ b_d,
       const float* __restrict__ Wr,    const float* __restrict__ br,
       const float* __restrict__ z,     float* __restrict__ out)
{
  __shared__ SMem sm;
  const int tid  = threadIdx.x;
  const int lane = tid & 63;
  const int wv   = tid >> 6;        // 0..15
  const int j    = wv & 7;          // col tile
  const int G    = wv >> 3;         // row group
  const int cc   = lane & 15;
  const int qd   = lane >> 4;
  const int R0   = blockIdx.x * ROWS;
  const int colj = j * 16 + cc;
  const int hrow0= G * 16 + qd * 4;
  const int rowA = G * 16 + cc;
  const float sg4[4] = {-L2E, -L2E, -TL2E, -L2E};

  unsigned int (*offsb)[ROWS] = (unsigned int(*)[ROWS])sm.ub;             // 6400
  unsigned int*   cl0 = (unsigned int*)(sm.ub + 6400);                    // 2048
  unsigned short* cl1 = (unsigned short*)(sm.ub + 8448);                  // 1024
  float (*offlast)[2] = (float(*)[2])(sm.ub + 9472);                      // 256
  float (*delta)[2]   = (float(*)[2])(sm.ub + 9728);                      // 256
  float (*outst)[CHUNK][2] = (float(*)[CHUNK][2])sm.ub;                   // 10240 (decoder)

  // ================= prep =================
  for (int i = tid; i < TOBS * ROWS; i += 1024){
    int t = i >> 5, row = i & 31;
    const float* ob = obs + (size_t)(R0 + row) * (TOBS * 2) + t * 2;
    float o0 = ob[0], o1 = ob[1];
    if (t){ o0 -= ob[-2]; o1 -= ob[-1]; }
    offsb[t][row] = pkbf(o0, o1);
    if (t == TOBS - 1){ offlast[row][0] = o0; offlast[row][1] = o1; }
  }
  for (int i = tid; i < ROWS * KPAD / 2; i += 1024)
    ((unsigned int*)&sm.h[0][0])[i] = 0u;
  if (tid < 512){
    const float* wr = Wih_e + tid * EMB;
    float w0 = 0.f, w1 = 0.f, bb = b_e[tid];
    for (int e = 0; e < EMB; ++e){
      float w = wr[e];
      w0 += w * We[e*2]; w1 += w * We[e*2+1]; bb += w * be[e];
    }
    cl0[tid] = pkbf(bb, w0); cl1[tid] = bfs(w1);
  }
  // stage encoder Whh B-frags into LDS (pre-scaled per gate)
  #pragma unroll
  for (int i = 0; i < 8; ++i){
    int f = tid + i * 1024;
    int j_ = f >> 10, g_ = (f >> 8) & 3, kt_ = (f >> 6) & 3, l_ = f & 63;
    int n = g_*128 + j_*16 + (l_ & 15);
    int k = kt_*32 + (l_ >> 4)*8;
    sm.wfr[j_][g_][kt_][l_] = __builtin_bit_cast(uint4,
        pack8s(Whh_e + (size_t)n * HID + k, sg4[g_]));
  }
  __syncthreads();

  // per-wave encoder input consts (pre-scaled)
  float bcs[4], w0s[4], w1s[4];
  #pragma unroll
  for (int g = 0; g < 4; ++g){
    int n = g*128 + colj;
    unsigned int c0 = cl0[n];
    bcs[g] = sg4[g] * lo2f(c0);
    w0s[g] = sg4[g] * hi2f(c0);
    w1s[g] = sg4[g] * lo2f((unsigned int)cl1[n]);
  }
  f32x4 acc[4];
  float cst[4] = {0.f, 0.f, 0.f, 0.f};
  const uint4* wj = &sm.wfr[j][0][0][lane];   // (g,kt) stride = 64 uint4

  // ================= encoder: 50 steps =================
  #pragma unroll 1
  for (int t = 0; t < TOBS; ++t){
    const int par = t & 1;
    {
      uint4 ou = *(const uint4*)&offsb[t][hrow0];
      float o0v[4] = {lo2f(ou.x), lo2f(ou.y), lo2f(ou.z), lo2f(ou.w)};
      float o1v[4] = {hi2f(ou.x), hi2f(ou.y), hi2f(ou.z), hi2f(ou.w)};
      #pragma unroll
      for (int g = 0; g < 4; ++g)
        #pragma unroll
        for (int r = 0; r < 4; ++r)
          acc[g][r] = __builtin_fmaf(w0s[g], o0v[r], __builtin_fmaf(w1s[g], o1v[r], bcs[g]));
    }
    const unsigned short* hb = &sm.h[par][0];
    #pragma unroll
    for (int kt = 0; kt < 4; ++kt){
      bf16x8 af = *(const bf16x8*)&hb[rowA*KPAD + kt*32 + qd*8];
      #pragma unroll
      for (int g = 0; g < 4; ++g)
        acc[g] = MFMA(af, __builtin_bit_cast(bf16x8, wj[(g*4 + kt)*64]), acc[g], 0,0,0);
    }
    unsigned short* hn = &sm.h[par ^ 1][0];
    ELEM_R(0); ELEM_R(1); ELEM_R(2); ELEM_R(3);
    __syncthreads();
  }
  // hF in sm.h[0]

  // ================= MLP =================
  {
    unsigned short* h1 = (unsigned short*)&sm.wfr[0][0][0][0];
    const int n1 = wv*16 + cc;             // 0..255
    float b = bm1[n1];
    #pragma unroll
    for (int Gp = 0; Gp < 2; ++Gp){
      f32x4 a1 = {b, b, b, b};
      #pragma unroll
      for (int kt = 0; kt < 4; ++kt){
        bf16x8 af = *(const bf16x8*)&sm.h[0][(Gp*16 + cc)*KPAD + kt*32 + qd*8];
        a1 = MFMA(af, pack8(Wm1 + (size_t)n1 * HID + kt*32 + qd*8), a1, 0,0,0);
      }
      #pragma unroll
      for (int r = 0; r < 4; ++r){
        float v = a1[r]; v = v > 0.f ? v : 0.f;
        h1[(Gp*16 + qd*4 + r)*H1PAD + n1] = bfs(v);
      }
    }
  }
  __syncthreads();
  {
    const unsigned short* h1 = (const unsigned short*)&sm.wfr[0][0][0][0];
    if (wv < 7){
      const int n2 = wv*16 + cc;           // 0..111
      float b = bm2[n2];
      #pragma unroll
      for (int Gp = 0; Gp < 2; ++Gp){
        f32x4 a2 = {b, b, b, b};
        #pragma unroll
        for (int kt = 0; kt < 8; ++kt){
          bf16x8 af = *(const bf16x8*)&h1[(Gp*16 + cc)*H1PAD + kt*32 + qd*8];
          a2 = MFMA(af, pack8(Wm2 + (size_t)n2 * MD + kt*32 + qd*8), a2, 0,0,0);
        }
        #pragma unroll
        for (int r = 0; r < 4; ++r){
          float v = a2[r]; v = v > 0.f ? v : 0.f;
          sm.h[0][(Gp*16 + qd*4 + r)*KPAD + n2] = bfs(v);
        }
      }
    }
    if (tid < 512){
      int row = tid >> 4, nz = tid & 15;
      sm.h[0][row*KPAD + M2N + nz] = bfs(z[(size_t)(R0 + row)*NZ + nz]);
    }
  }
  __syncthreads();   // dh complete in h[0]; h1 reads done -> wfr writable

  // ================= decoder prep =================
  if (tid < 512){
    const float* wr = Wih_d + tid * EMB;
    float w0 = 0.f, w1 = 0.f, bb = b_d[tid];
    for (int e = 0; e < EMB; ++e){
      float w = wr[e];
      w0 += w * Wd[e*2]; w1 += w * Wd[e*2+1]; bb += w * bd[e];
    }
    cl0[tid] = pkbf(bb, w0); cl1[tid] = bfs(w1);
  }
  __syncthreads();
  // stage decoder B-frags: s_g*(Whh_d + u0(x)Wr0 + u1(x)Wr1)
  #pragma unroll
  for (int i = 0; i < 8; ++i){
    int f = tid + i * 1024;
    int j_ = f >> 10, g_ = (f >> 8) & 3, kt_ = (f >> 6) & 3, l_ = f & 63;
    int n = g_*128 + j_*16 + (l_ & 15);
    int k = kt_*32 + (l_ >> 4)*8;
    unsigned int c0 = cl0[n];
    float w0 = hi2f(c0);
    float w1 = lo2f((unsigned int)cl1[n]);
    float s = sg4[g_];
    const float* pw = Whh_d + (size_t)n * HID + k;
    float4 fa = *(const float4*)pw,        fb = *(const float4*)(pw + 4);
    float4 wa = *(const float4*)(Wr + k),  wb = *(const float4*)(Wr + k + 4);
    float4 va = *(const float4*)(Wr + HID + k), vb = *(const float4*)(Wr + HID + k + 4);
    uint4 uu;
    uu.x = pkbf(s*(fa.x + w0*wa.x + w1*va.x), s*(fa.y + w0*wa.y + w1*va.y));
    uu.y = pkbf(s*(fa.z + w0*wa.z + w1*va.z), s*(fa.w + w0*wa.w + w1*va.w));
    uu.z = pkbf(s*(fb.x + w0*wb.x + w1*vb.x), s*(fb.y + w0*wb.y + w1*vb.y));
    uu.w = pkbf(s*(fb.z + w0*wb.z + w1*vb.z), s*(fb.w + w0*wb.w + w1*vb.w));
    sm.wfr[j_][g_][kt_][l_] = uu;
  }
  if (wv == 1){   // readout Wr B-frags
    #pragma unroll
    for (int kt = 0; kt < 4; ++kt){
      uint4 uu = __builtin_bit_cast(uint4, pack8(Wr + (size_t)(cc & 1)*HID + kt*32 + qd*8));
      if (cc >= 2){ uu.x = 0u; uu.y = 0u; uu.z = 0u; uu.w = 0u; }
      sm.b5f[kt][lane] = uu;
    }
  }
  __syncthreads();

  const float br0 = br[0], br1 = br[1];
  const float brc = (cc == 0) ? br0 : br1;
  // decoder consts (civs = feedback-folded bias; w0d/w1d live only through the peel)
  float civs[4], w0d[4], w1d[4];
  #pragma unroll
  for (int g = 0; g < 4; ++g){
    int n = g*128 + colj;
    unsigned int c0 = cl0[n];
    float bb = lo2f(c0), w0 = hi2f(c0), w1 = lo2f((unsigned int)cl1[n]);
    civs[g] = sg4[g] * (bb + w0*br0 + w1*br1);
    w0d[g] = sg4[g] * w0; w1d[g] = sg4[g] * w1;
  }
  const bool owner = (wv == 1) || (wv == 14);   // wv1:(j1,G0) SIMD1, wv14:(j6,G1) SIMD2
  float cum[4] = {0.f,0.f,0.f,0.f};
  if (owner){
    f32x4 a5 = {0.f, 0.f, 0.f, 0.f};
    #pragma unroll
    for (int kt = 0; kt < 4; ++kt){
      bf16x8 af = *(const bf16x8*)&sm.h[0][rowA*KPAD + kt*32 + qd*8];
      a5 = MFMA(af, __builtin_bit_cast(bf16x8, sm.b5f[kt][lane]), a5, 0,0,0);
    }
    if (cc < 2){
      #pragma unroll
      for (int r = 0; r < 4; ++r){
        delta[hrow0 + r][cc] = offlast[hrow0 + r][cc] - (a5[r] + brc);
        cum[r] = obs[(size_t)(R0 + hrow0 + r)*(TOBS*2) + (TOBS-1)*2 + cc];
      }
    }
  }
  #pragma unroll
  for (int r = 0; r < 4; ++r) cst[r] = 0.f;
  __syncthreads();

  // ---- decoder step 0 (peeled: delta input path) ----
  {
    float4 dA = *(const float4*)&delta[hrow0][0];
    float4 dB = *(const float4*)&delta[hrow0 + 2][0];
    float d0v[4] = {dA.x, dA.z, dB.x, dB.z};
    float d1v[4] = {dA.y, dA.w, dB.y, dB.w};
    #pragma unroll
    for (int g = 0; g < 4; ++g)
      #pragma unroll
      for (int r = 0; r < 4; ++r)
        acc[g][r] = __builtin_fmaf(w0d[g], d0v[r], __builtin_fmaf(w1d[g], d1v[r], civs[g]));
    const unsigned short* hb = &sm.h[0][0];
    #pragma unroll
    for (int kt = 0; kt < 4; ++kt){
      bf16x8 af = *(const bf16x8*)&hb[rowA*KPAD + kt*32 + qd*8];
      #pragma unroll
      for (int g = 0; g < 4; ++g)
        acc[g] = MFMA(af, __builtin_bit_cast(bf16x8, wj[(g*4 + kt)*64]), acc[g], 0,0,0);
    }
    unsigned short* hn = &sm.h[1][0];
    ELEM_R(0); ELEM_R(1); ELEM_R(2); ELEM_R(3);
    __syncthreads();
  }

  // ================= decoder: steps 1..99 =================
  #pragma unroll 1
  for (int s = 1; s < SDEC; ++s){
    if (s == 41 || s == 81){   // flush a completed 40-step chunk to HBM
      int b = (s == 41) ? 0 : CHUNK;
      for (int i = tid; i < ROWS * CHUNK; i += 1024){
        int row = i / CHUNK, k2 = i % CHUNK;
        *(float2*)(out + ((size_t)(R0 + row)*SDEC + b + k2)*2) = *(const float2*)&outst[row][k2][0];
      }
      __syncthreads();
    }
    const int par = s & 1;
    const unsigned short* hb = &sm.h[par][0];
    #pragma unroll
    for (int g = 0; g < 4; ++g){
      acc[g][0] = civs[g]; acc[g][1] = civs[g]; acc[g][2] = civs[g]; acc[g][3] = civs[g];
    }
    #pragma unroll
    for (int kt = 0; kt < 4; ++kt){
      bf16x8 af = *(const bf16x8*)&hb[rowA*KPAD + kt*32 + qd*8];
      #pragma unroll
      for (int g = 0; g < 4; ++g)
        acc[g] = MFMA(af, __builtin_bit_cast(bf16x8, wj[(g*4 + kt)*64]), acc[g], 0,0,0);
    }
    unsigned short* hn = &sm.h[par ^ 1][0];
    ELEM_R(0); ELEM_R(1); ELEM_R(2); ELEM_R(3);
    if (owner){   // readout h_{s-1}: off = Wr.h + br -> cumsum -> LDS chunk
      f32x4 a5 = {brc, brc, brc, brc};
      #pragma unroll
      for (int kt = 0; kt < 4; ++kt){
        bf16x8 af = *(const bf16x8*)&hb[rowA*KPAD + kt*32 + qd*8];
        a5 = MFMA(af, __builtin_bit_cast(bf16x8, sm.b5f[kt][lane]), a5, 0,0,0);
      }
      if (cc < 2){
        int slot = (s - 1) % CHUNK;
        #pragma unroll
        for (int r = 0; r < 4; ++r){
          cum[r] += a5[r];
          outst[hrow0 + r][slot][cc] = cum[r];
        }
      }
    }
    __syncthreads();
  }

  // epilogue: pred[S-1] from h[0] (= h_99) -> slot 19
  if (owner){
    f32x4 a5 = {brc, brc, brc, brc};
    #pragma unroll
    for (int kt = 0; kt < 4; ++kt){
      bf16x8 af = *(const bf16x8*)&sm.h[0][rowA*KPAD + kt*32 + qd*8];
      a5 = MFMA(af, __builtin_bit_cast(bf16x8, sm.b5f[kt][lane]), a5, 0,0,0);
    }
    if (cc < 2){
      #pragma unroll
      for (int r = 0; r < 4; ++r)
        outst[hrow0 + r][(SDEC - 1) % CHUNK][cc] = cum[r] + a5[r];
    }
  }
  __syncthreads();

  // final flush: steps 80..99 (slots 0..19)
  for (int i = tid; i < ROWS * 20; i += 1024){
    int row = i / 20, k2 = i % 20;
    *(float2*)(out + ((size_t)(R0 + row)*SDEC + 80 + k2)*2) = *(const float2*)&outst[row][k2][0];
  }
}

extern "C" void kernel_launch(void* const* d_in, const int* in_sizes, int n_in,
                              void* d_out, int out_size, void* d_ws, size_t ws_size,
                              hipStream_t stream) {
  (void)in_sizes; (void)n_in; (void)d_ws; (void)ws_size; (void)out_size;
  const float* obs   = (const float*)d_in[0];
  // d_in[1] = num_steps (100), compile-time constant here
  const float* We    = (const float*)d_in[2];
  const float* be    = (const float*)d_in[3];
  const float* Wih_e = (const float*)d_in[4];
  const float* Whh_e = (const float*)d_in[5];
  const float* b_e   = (const float*)d_in[6];
  const float* Wm1   = (const float*)d_in[7];
  const float* bm1   = (const float*)d_in[8];
  const float* Wm2   = (const float*)d_in[9];
  const float* bm2   = (const float*)d_in[10];
  const float* Wd    = (const float*)d_in[11];
  const float* bd    = (const float*)d_in[12];
  const float* Wih_d = (const float*)d_in[13];
  const float* Whh_d = (const float*)d_in[14];
  const float* b_d   = (const float*)d_in[15];
  const float* Wr    = (const float*)d_in[16];
  const float* br    = (const float*)d_in[17];
  const float* zz    = (const float*)d_in[18];
  hipLaunchKernelGGL(seqgen, dim3(8192 / ROWS), dim3(1024), 0, stream,
                     obs, We, be, Wih_e, Whh_e, b_e, Wm1, bm1, Wm2, bm2,
                     Wd, bd, Wih_d, Whh_d, b_d, Wr, br, zz, (float*)d_out);
}

// Round 14
// 482.248 us; speedup vs baseline: 1.2295x; 1.2295x over previous
//
#include <hip/hip_runtime.h>

#define TOBS  50
#define SDEC  100
#define HID   128
#define EMB   64
#define MD    256
#define M2N   112
#define NZ    16
#define ROWS  32
#define KPAD  140           // shorts; 70-dw row stride (proven low-conflict R2-R13)
#define H1PAD 268
#define L2E   1.4426950408889634f
#define TL2E  2.8853900817779268f

using bf16x8 = __attribute__((ext_vector_type(8))) short;
using f32x4  = __attribute__((ext_vector_type(4))) float;
#define MFMA __builtin_amdgcn_mfma_f32_16x16x32_bf16

struct alignas(16) SMem {
  unsigned short h[2][ROWS * KPAD];      // 17920 B  h double buffer (bf16)
  unsigned int offsb[TOBS][ROWS];        //  6400 B  encoder offsets (bf16x2)
  union {
    float4 cl[512];                      //  8192 B  fused input consts
    unsigned short h1[ROWS * H1PAD];     // 17152 B  MLP hidden
    float outst[ROWS][SDEC][2];          // 25600 B  decoder output staging
  } u;
  uint4 b5f[64][5];                      //  5120 B  readout Wr frags (stride 5)
  float offlast[ROWS][2];
  float delta[ROWS][2];
};

__device__ __forceinline__ unsigned int rnd16(float x){
  return __builtin_bit_cast(unsigned int, x) + 0x8000u;
}
__device__ __forceinline__ unsigned int pkbf(float a, float b){
  return __builtin_amdgcn_perm(rnd16(b), rnd16(a), 0x07060302u);
}
__device__ __forceinline__ unsigned short bfs(float x){ return (unsigned short)(rnd16(x) >> 16); }
__device__ __forceinline__ float rcpf(float x){ return __builtin_amdgcn_rcpf(x); }
__device__ __forceinline__ float ex2(float x){ return __builtin_amdgcn_exp2f(x); }
__device__ __forceinline__ bf16x8 pack8s(const float* p, float s){
  float4 a = *(const float4*)(p);
  float4 b = *(const float4*)(p + 4);
  uint4 u;
  u.x = pkbf(s*a.x, s*a.y); u.y = pkbf(s*a.z, s*a.w);
  u.z = pkbf(s*b.x, s*b.y); u.w = pkbf(s*b.z, s*b.w);
  return __builtin_bit_cast(bf16x8, u);
}
__device__ __forceinline__ bf16x8 pack8(const float* p){ return pack8s(p, 1.0f); }

// ---- staged LSTM elementwise pieces (per 4-row chunk) ----
// SI: ei = ex2(acc_i)          SF: a1 = 1+ex2(acc_f)
// SG: c-update -> em = ex2(-2c*log2e)    SO: h = sig(o)*tanh(c) -> LDS
#define SI(ACC, EI) do { _Pragma("unroll") \
  for (int r_ = 0; r_ < 4; ++r_) EI[r_] = ex2(ACC[r_]); } while(0)
#define SF(ACC, A1) do { _Pragma("unroll") \
  for (int r_ = 0; r_ < 4; ++r_) A1[r_] = 1.0f + ex2(ACC[r_]); } while(0)
#define SG(ACC, EI, A1, CST, EM) do { _Pragma("unroll") \
  for (int r_ = 0; r_ < 4; ++r_){ \
    float eg_ = ex2(ACC[r_]); \
    float P_  = (1.0f + EI[r_]) * (1.0f + eg_); \
    float rD_ = rcpf(A1[r_] * P_); \
    float N_  = __builtin_fmaf(CST[r_], P_, (1.0f - eg_) * A1[r_]); \
    float cn_ = N_ * rD_; CST[r_] = cn_; \
    EM[r_] = ex2(cn_ * (-TL2E)); } } while(0)
#define SO(ACC, EM, HN, ROWB) do { _Pragma("unroll") \
  for (int r_ = 0; r_ < 4; ++r_){ \
    float eo_ = ex2(ACC[r_]); \
    float rQ_ = rcpf((1.0f + eo_) * (1.0f + EM[r_])); \
    float hh_ = (1.0f - EM[r_]) * rQ_; \
    HN[((ROWB) + r_)*KPAD + colj] = bfs(hh_); } } while(0)

// gate chain with MFMA-folded input (encoder / decoder-peel)
#define GCHAIN(DST, AF, A5, BX, G) do { \
  DST = MFMA(A5, BX[G], zz4, 0,0,0); \
  _Pragma("unroll") for (int kt_ = 0; kt_ < 4; ++kt_) \
    DST = MFMA(AF[kt_], bfr[G][kt_], DST, 0,0,0); } while(0)
// gate chain with C-operand bias init (decoder steady)
#define DCHAIN(DST, AF, G) do { \
  DST[0]=civs[G]; DST[1]=civs[G]; DST[2]=civs[G]; DST[3]=civs[G]; \
  _Pragma("unroll") for (int kt_ = 0; kt_ < 4; ++kt_) \
    DST = MFMA(AF[kt_], bfr[G][kt_], DST, 0,0,0); } while(0)

extern "C" __global__ void __launch_bounds__(512, 2)
seqgen(const float* __restrict__ obs,
       const float* __restrict__ We,    const float* __restrict__ be,
       const float* __restrict__ Wih_e, const float* __restrict__ Whh_e, const float* __restrict__ b_e,
       const float* __restrict__ Wm1,   const float* __restrict__ bm1,
       const float* __restrict__ Wm2,   const float* __restrict__ bm2,
       const float* __restrict__ Wd,    const float* __restrict__ bd,
       const float* __restrict__ Wih_d, const float* __restrict__ Whh_d, const float* __restrict__ b_d,
       const float* __restrict__ Wr,    const float* __restrict__ br,
       const float* __restrict__ z,     float* __restrict__ out)
{
  __shared__ SMem sm;
  const int tid  = threadIdx.x;
  const int lane = tid & 63;
  const int jq   = tid >> 6;
  const int cc   = lane & 15;
  const int qd   = lane >> 4;
  const bool q0  = (qd == 0);
  const int R0   = blockIdx.x * ROWS;
  const int colj = jq * 16 + cc;
  const unsigned int one_q0 = q0 ? 0x3F80u : 0u;
  const float sg4[4] = {-L2E, -L2E, -TL2E, -L2E};

  // ---------------- prep ----------------
  for (int i = tid; i < TOBS * ROWS; i += 512){
    int t = i >> 5, row = i & 31;
    const float* ob = obs + (size_t)(R0 + row) * (TOBS * 2) + t * 2;
    float o0 = ob[0], o1 = ob[1];
    if (t){ o0 -= ob[-2]; o1 -= ob[-1]; }
    sm.offsb[t][row] = pkbf(o0, o1);
    if (t == TOBS - 1){ sm.offlast[row][0] = o0; sm.offlast[row][1] = o1; }
  }
  for (int i = tid; i < ROWS * KPAD / 2; i += 512)
    ((unsigned int*)&sm.h[0][0])[i] = 0u;
  {
    const float* wr = Wih_e + tid * EMB;
    float w0 = 0.f, w1 = 0.f, bb = b_e[tid];
    for (int e = 0; e < EMB; ++e){
      float w = wr[e];
      w0 += w * We[e*2]; w1 += w * We[e*2+1]; bb += w * be[e];
    }
    sm.u.cl[tid] = make_float4(bb, w0, w1, 0.f);
  }
  __syncthreads();

  bf16x8 bfr[4][4];
  #pragma unroll
  for (int kt = 0; kt < 4; ++kt)
    #pragma unroll
    for (int g = 0; g < 4; ++g)
      bfr[g][kt] = pack8s(Whh_e + (size_t)(g*128 + colj) * HID + kt*32 + qd*8, sg4[g]);

  const f32x4 zz4 = {0.f, 0.f, 0.f, 0.f};
  float cst0[4] = {0.f,0.f,0.f,0.f}, cst1[4] = {0.f,0.f,0.f,0.f};
  float ei[4], a1v[4], em[4];

  // ================= encoder: 50 steps, gate-staged interleave =================
  {
    bf16x8 b5x[4];
    #pragma unroll
    for (int g = 0; g < 4; ++g){
      float4 v = sm.u.cl[g*128 + colj];
      float s = sg4[g];
      uint4 w;
      w.x = q0 ? pkbf(s*v.y, s*v.z) : 0u;
      w.y = q0 ? (rnd16(s*v.x) >> 16) : 0u;
      w.z = 0u; w.w = 0u;
      b5x[g] = __builtin_bit_cast(bf16x8, w);
    }
    #pragma unroll 1
    for (int t = 0; t < TOBS; ++t){
      const int par = t & 1;
      const unsigned short* hb = &sm.h[par][0];
      unsigned short* hn = &sm.h[par ^ 1][0];
      bf16x8 af0[4], af1[4];
      #pragma unroll
      for (int kt = 0; kt < 4; ++kt)
        af0[kt] = *(const bf16x8*)&hb[cc*KPAD + kt*32 + qd*8];
      uint4 a0i; a0i.x = q0 ? sm.offsb[t][cc] : 0u; a0i.y = one_q0; a0i.z = 0u; a0i.w = 0u;
      bf16x8 a50 = __builtin_bit_cast(bf16x8, a0i);
      f32x4 aI, aF, aG, aO;
      GCHAIN(aI, af0, a50, b5x, 0);
      #pragma unroll
      for (int kt = 0; kt < 4; ++kt)
        af1[kt] = *(const bf16x8*)&hb[(16 + cc)*KPAD + kt*32 + qd*8];
      GCHAIN(aF, af0, a50, b5x, 1);
      SI(aI, ei);
      GCHAIN(aG, af0, a50, b5x, 2);
      SF(aF, a1v);
      GCHAIN(aO, af0, a50, b5x, 3);
      SG(aG, ei, a1v, cst0, em);
      uint4 a1i; a1i.x = q0 ? sm.offsb[t][16 + cc] : 0u; a1i.y = one_q0; a1i.z = 0u; a1i.w = 0u;
      bf16x8 a51 = __builtin_bit_cast(bf16x8, a1i);
      f32x4 bI, bF, bG, bO;
      GCHAIN(bI, af1, a51, b5x, 0);
      SO(aO, em, hn, qd*4);
      GCHAIN(bF, af1, a51, b5x, 1);
      GCHAIN(bG, af1, a51, b5x, 2);
      SI(bI, ei);
      GCHAIN(bO, af1, a51, b5x, 3);
      SF(bF, a1v);
      SG(bG, ei, a1v, cst1, em);
      SO(bO, em, hn, 16 + qd*4);
      __syncthreads();
    }
  }
  // hF in sm.h[0]

  // ================= MLP =================
  {
    bf16x8 af[2][4];
    #pragma unroll
    for (int G = 0; G < 2; ++G)
      #pragma unroll
      for (int kt = 0; kt < 4; ++kt)
        af[G][kt] = *(const bf16x8*)&sm.h[0][(G*16 + cc)*KPAD + kt*32 + qd*8];
    f32x4 a1[2][2];
    #pragma unroll
    for (int t2 = 0; t2 < 2; ++t2){
      const int n = jq*32 + t2*16 + cc;
      float b = bm1[n];
      #pragma unroll
      for (int G = 0; G < 2; ++G){ a1[t2][G][0]=b; a1[t2][G][1]=b; a1[t2][G][2]=b; a1[t2][G][3]=b; }
      #pragma unroll
      for (int kt = 0; kt < 4; ++kt){
        bf16x8 wb = pack8(Wm1 + (size_t)n * HID + kt*32 + qd*8);
        a1[t2][0] = MFMA(af[0][kt], wb, a1[t2][0], 0,0,0);
        a1[t2][1] = MFMA(af[1][kt], wb, a1[t2][1], 0,0,0);
      }
    }
    __syncthreads();
    #pragma unroll
    for (int t2 = 0; t2 < 2; ++t2)
      #pragma unroll
      for (int G = 0; G < 2; ++G)
        #pragma unroll
        for (int r = 0; r < 4; ++r){
          float v = a1[t2][G][r]; v = v > 0.f ? v : 0.f;
          sm.u.h1[(G*16 + qd*4 + r)*H1PAD + jq*32 + t2*16 + cc] = bfs(v);
        }
  }
  __syncthreads();
  {
    bf16x8 af2[2][8];
    #pragma unroll
    for (int G = 0; G < 2; ++G)
      #pragma unroll
      for (int kt = 0; kt < 8; ++kt)
        af2[G][kt] = *(const bf16x8*)&sm.u.h1[(G*16 + cc)*H1PAD + kt*32 + qd*8];
    if (jq < 7){
      const int n2 = jq*16 + cc;
      float b = bm2[n2];
      f32x4 a2[2];
      #pragma unroll
      for (int G = 0; G < 2; ++G){ a2[G][0]=b; a2[G][1]=b; a2[G][2]=b; a2[G][3]=b; }
      #pragma unroll
      for (int kt = 0; kt < 8; ++kt){
        bf16x8 wb = pack8(Wm2 + (size_t)n2 * MD + kt*32 + qd*8);
        a2[0] = MFMA(af2[0][kt], wb, a2[0], 0,0,0);
        a2[1] = MFMA(af2[1][kt], wb, a2[1], 0,0,0);
      }
      #pragma unroll
      for (int G = 0; G < 2; ++G)
        #pragma unroll
        for (int r = 0; r < 4; ++r){
          float v = a2[G][r]; v = v > 0.f ? v : 0.f;
          sm.h[0][(G*16 + qd*4 + r)*KPAD + jq*16 + cc] = bfs(v);
        }
    }
    {
      int row = tid >> 4, nz = tid & 15;
      sm.h[0][row*KPAD + M2N + nz] = bfs(z[(size_t)(R0 + row)*NZ + nz]);
    }
  }
  __syncthreads();   // dh complete in h[0]

  // ================= decoder prep =================
  {
    const float* wr = Wih_d + tid * EMB;
    float w0 = 0.f, w1 = 0.f, bb = b_d[tid];
    for (int e = 0; e < EMB; ++e){
      float w = wr[e];
      w0 += w * Wd[e*2]; w1 += w * Wd[e*2+1]; bb += w * bd[e];
    }
    sm.u.cl[tid] = make_float4(bb, w0, w1, 0.f);
  }
  const float br0 = br[0], br1 = br[1];
  const float brc = (cc == 0) ? br0 : br1;
  if (jq == 1){   // readout Wr fragments + step-0 delta
    uint4 bq[4];
    #pragma unroll
    for (int kt = 0; kt < 4; ++kt){
      bf16x8 f = pack8(Wr + (size_t)(cc & 1)*HID + kt*32 + qd*8);
      uint4 uu = __builtin_bit_cast(uint4, f);
      if (cc >= 2){ uu.x = 0u; uu.y = 0u; uu.z = 0u; uu.w = 0u; }
      bq[kt] = uu;
      sm.b5f[lane][kt] = uu;
    }
    #pragma unroll
    for (int G = 0; G < 2; ++G){
      bf16x8 afd[4];
      #pragma unroll
      for (int kt = 0; kt < 4; ++kt)
        afd[kt] = *(const bf16x8*)&sm.h[0][(G*16 + cc)*KPAD + kt*32 + qd*8];
      f32x4 a5 = zz4;
      #pragma unroll
      for (int kt = 0; kt < 4; ++kt)
        a5 = MFMA(afd[kt], __builtin_bit_cast(bf16x8, bq[kt]), a5, 0,0,0);
      if (cc < 2){
        #pragma unroll
        for (int r = 0; r < 4; ++r){
          int row = G*16 + qd*4 + r;
          sm.delta[row][cc] = sm.offlast[row][cc] - (a5[r] + brc);
        }
      }
    }
  }
  __syncthreads();

  // decoder consts: civs (feedback-folded bias) + bfr' = s_g*(Whh_d + u0(x)Wr0 + u1(x)Wr1)
  float civs[4];
  #pragma unroll
  for (int g = 0; g < 4; ++g){
    float4 v = sm.u.cl[g*128 + colj];
    civs[g] = sg4[g] * (v.x + v.y*br0 + v.z*br1);
  }
  #pragma unroll
  for (int kt = 0; kt < 4; ++kt){
    const int kb = kt*32 + qd*8;
    float4 wa = *(const float4*)(Wr + kb),       wb2 = *(const float4*)(Wr + kb + 4);
    float4 va = *(const float4*)(Wr + HID + kb), vb2 = *(const float4*)(Wr + HID + kb + 4);
    #pragma unroll
    for (int g = 0; g < 4; ++g){
      float4 v = sm.u.cl[g*128 + colj];
      const float w0g = v.y, w1g = v.z;
      const float* pp = Whh_d + (size_t)(g*128 + colj) * HID + kb;
      float4 fa = *(const float4*)pp, fb = *(const float4*)(pp + 4);
      float s = sg4[g];
      uint4 uu;
      uu.x = pkbf(s*(fa.x + w0g*wa.x  + w1g*va.x),  s*(fa.y + w0g*wa.y  + w1g*va.y));
      uu.y = pkbf(s*(fa.z + w0g*wa.z  + w1g*va.z),  s*(fa.w + w0g*wa.w  + w1g*va.w));
      uu.z = pkbf(s*(fb.x + w0g*wb2.x + w1g*vb2.x), s*(fb.y + w0g*wb2.y + w1g*vb2.y));
      uu.w = pkbf(s*(fb.z + w0g*wb2.z + w1g*vb2.z), s*(fb.w + w0g*wb2.w + w1g*vb2.w));
      bfr[g][kt] = __builtin_bit_cast(bf16x8, uu);
    }
  }
  const int Gown = (jq == 3) ? 1 : 0;
  float cum[4] = {0.f,0.f,0.f,0.f};
  if ((jq == 1 || jq == 3) && cc < 2){
    #pragma unroll
    for (int r = 0; r < 4; ++r)
      cum[r] = obs[(size_t)(R0 + Gown*16 + qd*4 + r)*(TOBS*2) + (TOBS-1)*2 + cc];
  }
  #pragma unroll
  for (int r = 0; r < 4; ++r){ cst0[r] = 0.f; cst1[r] = 0.f; }
  __syncthreads();

  // ---- decoder step 0 (peeled: delta input path via MFMA; transients die after) ----
  {
    bf16x8 b5x[4];
    #pragma unroll
    for (int g = 0; g < 4; ++g){
      float4 v = sm.u.cl[g*128 + colj];
      float s = sg4[g];
      float bcp = v.x + v.y*br0 + v.z*br1;
      uint4 w;
      w.x = q0 ? pkbf(s*v.y, s*v.z) : 0u;
      w.y = q0 ? (rnd16(s*bcp) >> 16) : 0u;
      w.z = 0u; w.w = 0u;
      b5x[g] = __builtin_bit_cast(bf16x8, w);
    }
    uint4 c5; c5.x = 0u; c5.y = one_q0; c5.z = 0u; c5.w = 0u;
    float2 dv0 = *(const float2*)&sm.delta[cc][0];
    float2 dv1 = *(const float2*)&sm.delta[16 + cc][0];
    uint4 d0u = c5; d0u.x = q0 ? pkbf(dv0.x, dv0.y) : 0u;
    uint4 d1u = c5; d1u.x = q0 ? pkbf(dv1.x, dv1.y) : 0u;
    bf16x8 a50 = __builtin_bit_cast(bf16x8, d0u);
    bf16x8 a51 = __builtin_bit_cast(bf16x8, d1u);
    const unsigned short* hb = &sm.h[0][0];
    unsigned short* hn = &sm.h[1][0];
    bf16x8 af0[4], af1[4];
    #pragma unroll
    for (int kt = 0; kt < 4; ++kt)
      af0[kt] = *(const bf16x8*)&hb[cc*KPAD + kt*32 + qd*8];
    f32x4 aI, aF, aG, aO;
    GCHAIN(aI, af0, a50, b5x, 0);
    #pragma unroll
    for (int kt = 0; kt < 4; ++kt)
      af1[kt] = *(const bf16x8*)&hb[(16 + cc)*KPAD + kt*32 + qd*8];
    GCHAIN(aF, af0, a50, b5x, 1);
    SI(aI, ei);
    GCHAIN(aG, af0, a50, b5x, 2);
    SF(aF, a1v);
    GCHAIN(aO, af0, a50, b5x, 3);
    SG(aG, ei, a1v, cst0, em);
    f32x4 bI, bF, bG, bO;
    GCHAIN(bI, af1, a51, b5x, 0);
    SO(aO, em, hn, qd*4);
    GCHAIN(bF, af1, a51, b5x, 1);
    GCHAIN(bG, af1, a51, b5x, 2);
    SI(bI, ei);
    GCHAIN(bO, af1, a51, b5x, 3);
    SF(bF, a1v);
    SG(bG, ei, a1v, cst1, em);
    SO(bO, em, hn, 16 + qd*4);
    __syncthreads();
  }

  // ================= decoder: steps 1..99, gate-staged interleave =================
  #pragma unroll 1
  for (int s = 1; s < SDEC; ++s){
    const int par = s & 1;
    const unsigned short* hb = &sm.h[par][0];
    unsigned short* hn = &sm.h[par ^ 1][0];
    bf16x8 af0[4], af1[4];
    #pragma unroll
    for (int kt = 0; kt < 4; ++kt)
      af0[kt] = *(const bf16x8*)&hb[cc*KPAD + kt*32 + qd*8];
    f32x4 aI, aF, aG, aO;
    DCHAIN(aI, af0, 0);
    #pragma unroll
    for (int kt = 0; kt < 4; ++kt)
      af1[kt] = *(const bf16x8*)&hb[(16 + cc)*KPAD + kt*32 + qd*8];
    DCHAIN(aF, af0, 1);
    SI(aI, ei);
    DCHAIN(aG, af0, 2);
    SF(aF, a1v);
    DCHAIN(aO, af0, 3);
    SG(aG, ei, a1v, cst0, em);
    f32x4 bI, bF, bG, bO;
    DCHAIN(bI, af1, 0);
    SO(aO, em, hn, qd*4);
    DCHAIN(bF, af1, 1);
    DCHAIN(bG, af1, 2);
    SI(bI, ei);
    DCHAIN(bO, af1, 3);
    SF(bF, a1v);
    SG(bG, ei, a1v, cst1, em);
    SO(bO, em, hn, 16 + qd*4);
    // readout h_{s-1} (tail: matrix pipe free) -> cumsum -> LDS staging
    if (jq == 1 || jq == 3){
      f32x4 a5 = {brc, brc, brc, brc};
      #pragma unroll
      for (int kt = 0; kt < 4; ++kt){
        bf16x8 afx = (jq == 1) ? af0[kt] : af1[kt];
        a5 = MFMA(afx, __builtin_bit_cast(bf16x8, sm.b5f[lane][kt]), a5, 0,0,0);
      }
      if (cc < 2){
        #pragma unroll
        for (int r = 0; r < 4; ++r){
          cum[r] += a5[r];
          sm.u.outst[Gown*16 + qd*4 + r][s-1][cc] = cum[r];
        }
      }
    }
    __syncthreads();
  }

  // epilogue: pred[S-1] from h[0] (= h_99)
  if (jq == 1 || jq == 3){
    bf16x8 af[4];
    #pragma unroll
    for (int kt = 0; kt < 4; ++kt)
      af[kt] = *(const bf16x8*)&sm.h[0][(Gown*16 + cc)*KPAD + kt*32 + qd*8];
    f32x4 a5 = {brc, brc, brc, brc};
    #pragma unroll
    for (int kt = 0; kt < 4; ++kt)
      a5 = MFMA(af[kt], __builtin_bit_cast(bf16x8, sm.b5f[lane][kt]), a5, 0,0,0);
    if (cc < 2){
      #pragma unroll
      for (int r = 0; r < 4; ++r)
        sm.u.outst[Gown*16 + qd*4 + r][SDEC-1][cc] = cum[r] + a5[r];
    }
  }
  __syncthreads();

  // bulk write: LDS staging -> HBM, fully coalesced float2
  {
    const float2* src = (const float2*)&sm.u.outst[0][0][0];
    float2* dst = (float2*)(out + (size_t)R0 * SDEC * 2);
    for (int i = tid; i < ROWS * SDEC; i += 512)
      dst[i] = src[i];
  }
}

extern "C" void kernel_launch(void* const* d_in, const int* in_sizes, int n_in,
                              void* d_out, int out_size, void* d_ws, size_t ws_size,
                              hipStream_t stream) {
  (void)in_sizes; (void)n_in; (void)d_ws; (void)ws_size; (void)out_size;
  const float* obs   = (const float*)d_in[0];
  // d_in[1] = num_steps (100), compile-time constant here
  const float* We    = (const float*)d_in[2];
  const float* be    = (const float*)d_in[3];
  const float* Wih_e = (const float*)d_in[4];
  const float* Whh_e = (const float*)d_in[5];
  const float* b_e   = (const float*)d_in[6];
  const float* Wm1   = (const float*)d_in[7];
  const float* bm1   = (const float*)d_in[8];
  const float* Wm2   = (const float*)d_in[9];
  const float* bm2   = (const float*)d_in[10];
  const float* Wd    = (const float*)d_in[11];
  const float* bd    = (const float*)d_in[12];
  const float* Wih_d = (const float*)d_in[13];
  const float* Whh_d = (const float*)d_in[14];
  const float* b_d   = (const float*)d_in[15];
  const float* Wr    = (const float*)d_in[16];
  const float* br    = (const float*)d_in[17];
  const float* zz    = (const float*)d_in[18];
  hipLaunchKernelGGL(seqgen, dim3(8192 / ROWS), dim3(512), 0, stream,
                     obs, We, be, Wih_e, Whh_e, b_e, Wm1, bm1, Wm2, bm2,
                     Wd, bd, Wih_d, Whh_d, b_d, Wr, br, zz, (float*)d_out);
}